// Round 4
// baseline (13296.936 us; speedup 1.0000x reference)
//
#include <hip/hip_runtime.h>

typedef unsigned short u16;
typedef unsigned int u32;
typedef __attribute__((ext_vector_type(8))) short short8v;   // 8 bf16 (4 VGPR) MFMA frag
typedef __attribute__((ext_vector_type(4))) float f32x4;     // MFMA acc
typedef __attribute__((ext_vector_type(8))) u16 ush8;
typedef __attribute__((ext_vector_type(4))) u16 ush4;

__device__ __forceinline__ u16 f2bf(float x) {               // RNE f32->bf16
  u32 u = __builtin_bit_cast(u32, x);
  return (u16)((u + 0x7FFFu + ((u >> 16) & 1u)) >> 16);
}
__device__ __forceinline__ float bf2f(u16 h) {
  u32 u = ((u32)h) << 16;
  return __builtin_bit_cast(float, u);
}
__device__ __forceinline__ float sigm(float x) { return 1.f / (1.f + expf(-x)); }

typedef const __attribute__((address_space(1))) void gv_t;
typedef __attribute__((address_space(3))) void lv_t;
__device__ __forceinline__ void gload16(const void* g, void* l) {
  __builtin_amdgcn_global_load_lds((gv_t*)g, (lv_t*)l, 16, 0, 0);
}

// Device-scope grid barrier (all blocks co-resident: grid=256, 1 block/CU).
__device__ __forceinline__ void gridbar(int* bar, int nblk) {
  __syncthreads();
  if (threadIdx.x == 0) {
    __threadfence();                                  // release my writes
    int g = __hip_atomic_load(&bar[1], __ATOMIC_RELAXED, __HIP_MEMORY_SCOPE_AGENT);
    if (atomicAdd(&bar[0], 1) == nblk - 1) {
      bar[0] = 0;
      __threadfence();
      atomicAdd(&bar[1], 1);                          // release generation
    } else {
      while (__hip_atomic_load(&bar[1], __ATOMIC_RELAXED, __HIP_MEMORY_SCOPE_AGENT) == g)
        __builtin_amdgcn_s_sleep(2);
      __threadfence();                                // acquire
    }
  }
  __syncthreads();
}

// ---------------------------------------------------------------------------
// ConvLSTM recurrence: one WG per (b, row). Computes h for all t, stores
// split-bf16 h_vec rows [t*16+b][4096].  d = r*256 + ch*16 + col.
// ---------------------------------------------------------------------------
__global__ __launch_bounds__(256) void k_conv(int cin, int xmode,
    const float* __restrict__ xin, const float* __restrict__ cw,
    const float* __restrict__ cb, u16* __restrict__ hhi, u16* __restrict__ hlo)
{
  __shared__ float zb[32 * 18];        // cin x (16+2 pad)
  __shared__ float wb[64 * 32 * 3];
  __shared__ float bb[64];
  const int tid = threadIdx.x;
  const int b = blockIdx.x >> 4, r = blockIdx.x & 15;
  const int ch = tid >> 4, col = tid & 15;
  const int cx = cin - 16;
  for (int i = tid; i < 64 * cin * 3; i += 256) wb[i] = cw[i];
  if (tid < 64) bb[tid] = cb[tid];
  for (int i = tid; i < cin * 18; i += 256) zb[i] = 0.f;  // includes pad cols
  __syncthreads();
  float h = 0.f, c = 0.f;
  for (int t = 0; t < 128; ++t) {
    if (xmode == 0) {
      if (ch == 0) zb[col + 1] = xin[((long)b * 128 + t) * 256 + r * 16 + col];
    } else {
      zb[ch * 18 + col + 1] = xin[((long)t * 16 + b) * 4096 + r * 256 + ch * 16 + col];
    }
    zb[(cx + ch) * 18 + col + 1] = h;
    __syncthreads();
    float a0 = bb[ch], a1 = bb[16 + ch], a2 = bb[32 + ch], a3 = bb[48 + ch];
    for (int ic = 0; ic < cin; ++ic) {
      float z0 = zb[ic * 18 + col], z1 = zb[ic * 18 + col + 1], z2 = zb[ic * 18 + col + 2];
      const float* w0 = &wb[((0 * 16 + ch) * cin + ic) * 3];
      const float* w1 = &wb[((1 * 16 + ch) * cin + ic) * 3];
      const float* w2 = &wb[((2 * 16 + ch) * cin + ic) * 3];
      const float* w3 = &wb[((3 * 16 + ch) * cin + ic) * 3];
      a0 += z0 * w0[0] + z1 * w0[1] + z2 * w0[2];
      a1 += z0 * w1[0] + z1 * w1[1] + z2 * w1[2];
      a2 += z0 * w2[0] + z1 * w2[1] + z2 * w2[2];
      a3 += z0 * w3[0] + z1 * w3[1] + z2 * w3[2];
    }
    __syncthreads();
    c = sigm(a1) * c + sigm(a0) * tanhf(a2);   // i,f,g,o gate order
    h = sigm(a3) * tanhf(c);
    long idx = ((long)t * 16 + b) * 4096 + (long)r * 256 + ch * 16 + col;
    u16 hh = f2bf(h);
    hhi[idx] = hh;
    hlo[idx] = f2bf(h - bf2f(hh));
  }
}

// ---------------------------------------------------------------------------
// Transpose + split: W[4096][4096] fp32 (row k, col n) -> WT_hi/lo[n][k] bf16
// ---------------------------------------------------------------------------
__global__ __launch_bounds__(256) void k_tsplit(const float* __restrict__ W,
    u16* __restrict__ hi, u16* __restrict__ lo)
{
  __shared__ float tb[32][33];
  const int tn = blockIdx.x & 127, tk = blockIdx.x >> 7;
  const int n0 = tn * 32, k0 = tk * 32;
  const int lr = threadIdx.x >> 5, lc = threadIdx.x & 31;
  #pragma unroll
  for (int i = 0; i < 4; ++i)
    tb[lr + i * 8][lc] = W[(long)(k0 + lr + i * 8) * 4096 + n0 + lc];
  __syncthreads();
  #pragma unroll
  for (int i = 0; i < 4; ++i) {
    int n = lr + i * 8;
    float v = tb[lc][n];
    long idx = (long)(n0 + n) * 4096 + k0 + lc;
    u16 h = f2bf(v);
    hi[idx] = h;
    lo[idx] = f2bf(v - bf2f(h));
  }
}

// Elementwise split (no transpose) for wv
__global__ __launch_bounds__(256) void k_split(const float* __restrict__ W,
    u16* __restrict__ hi, u16* __restrict__ lo)
{
  long i = ((long)blockIdx.x * 256 + threadIdx.x) * 4;
  const float4 v = *(const float4*)&W[i];
  u16 h0 = f2bf(v.x), h1 = f2bf(v.y), h2 = f2bf(v.z), h3 = f2bf(v.w);
  ush4 hv = {h0, h1, h2, h3};
  ush4 lv = {f2bf(v.x - bf2f(h0)), f2bf(v.y - bf2f(h1)),
             f2bf(v.z - bf2f(h2)), f2bf(v.w - bf2f(h3))};
  *(ush4*)&hi[i] = hv;
  *(ush4*)&lo[i] = lv;
}

// ---------------------------------------------------------------------------
// Split-bf16 GEMM via global_load_lds + XOR-swizzled, DOUBLE-BUFFERED LDS.
// C[M][N] = A[M][4096] * B[N][4096]^T, A/B split hi/lo bf16. K = 4096.
// grid.x = mT * nTc + nT;  grid.y = batch (strided A/B/C).
// mode 0: fp32 C.  mode 1: split hi/lo bf16 C.
// ---------------------------------------------------------------------------
__global__ __launch_bounds__(256) void k_gemm(
    const u16* __restrict__ Ahi, const u16* __restrict__ Alo, long lda, long aBS,
    const u16* __restrict__ Bhi, const u16* __restrict__ Blo, long ldb, long bBS,
    float* __restrict__ Cf, u16* __restrict__ Chi, u16* __restrict__ Clo,
    long ldc, long cBS, int nTc, int mode)
{
  __shared__ __align__(16) u16 lds[2][16384];   // per buf: PA @0, PB @8192
  const int tid = threadIdx.x;
  const int lane = tid & 63;
  const int wv = tid >> 6;
  const int bx = blockIdx.x;
  const int nT = bx % nTc;
  const int mT = bx / nTc;
  const long aOff = (long)blockIdx.y * aBS;
  const long bOff = (long)blockIdx.y * bBS;
  const long cOff = (long)blockIdx.y * cBS;
  const long aRow0 = (long)mT * 128;
  const long bRow0 = (long)nT * 128;

  // per-lane pre-swizzled global staging source (rule #21: swz both sides)
  const int l8 = lane >> 3;             // row-within-8 AND swizzle key
  const int cslot = (lane & 7) ^ l8;    // logical chunk this lane fetches
  const int ck = (cslot & 3) * 8;
  const u16* aSrc = ((cslot < 4) ? Ahi : Alo) + aOff + (aRow0 + wv * 32 + l8) * lda + ck;
  const u16* bSrc = ((cslot < 4) ? Bhi : Blo) + bOff + (bRow0 + wv * 32 + l8) * ldb + ck;
  const int ldsAo = wv * 2048;          // wave wv stages rows wv*32..+31
  const int ldsBo = 8192 + wv * 2048;

  const int r15 = lane & 15, kq = lane >> 4;
  const int s7 = r15 & 7;
  const int oHi = (kq ^ s7) * 8;        // swizzled u16 offset of hi chunk
  const int oLo = ((4 + kq) ^ s7) * 8;  // swizzled u16 offset of lo chunk
  const int aQ = (wv >> 1) * 64;        // waveM*64
  const int bQ = (wv & 1) * 64;         // waveN*64

  f32x4 acc[4][4] = {};

#define STAGE(buf, kofs)                                                     \
  {                                                                          \
    const u16* sa = aSrc + (kofs);                                           \
    const u16* sb = bSrc + (kofs);                                           \
    u16* la = &lds[buf][ldsAo];                                              \
    u16* lb = &lds[buf][ldsBo];                                              \
    gload16(sa,            la);        gload16(sa +  8 * lda, la + 512);     \
    gload16(sa + 16 * lda, la + 1024); gload16(sa + 24 * lda, la + 1536);    \
    gload16(sb,            lb);        gload16(sb +  8 * ldb, lb + 512);     \
    gload16(sb + 16 * ldb, lb + 1024); gload16(sb + 24 * ldb, lb + 1536);    \
  }

  STAGE(0, 0)
  __syncthreads();                      // vmcnt(0) drained: buf0 ready
  int cur = 0;
  for (int k0 = 0; k0 < 4096; k0 += 32) {
    if (k0 + 32 < 4096) STAGE(cur ^ 1, k0 + 32)   // flies during MFMA phase
    const u16* L = &lds[cur][0];
    short8v bh[4], bl[4];
    #pragma unroll
    for (int j = 0; j < 4; ++j) {
      int rb = 8192 + (bQ + j * 16 + r15) * 64;
      bh[j] = *(const short8v*)&L[rb + oHi];
      bl[j] = *(const short8v*)&L[rb + oLo];
    }
    #pragma unroll
    for (int i = 0; i < 4; ++i) {
      int ra = (aQ + i * 16 + r15) * 64;
      short8v ah = *(const short8v*)&L[ra + oHi];
      short8v al = *(const short8v*)&L[ra + oLo];
      #pragma unroll
      for (int j = 0; j < 4; ++j) {
        acc[i][j] = __builtin_amdgcn_mfma_f32_16x16x32_bf16(ah, bh[j], acc[i][j], 0, 0, 0);
        acc[i][j] = __builtin_amdgcn_mfma_f32_16x16x32_bf16(ah, bl[j], acc[i][j], 0, 0, 0);
        acc[i][j] = __builtin_amdgcn_mfma_f32_16x16x32_bf16(al, bh[j], acc[i][j], 0, 0, 0);
      }
    }
    __syncthreads();   // next buf staged + all reads of cur done
    cur ^= 1;
  }
#undef STAGE
  // epilogue: D row=(lane>>4)*4+reg, col=lane&15 (measured m89 layout)
  const long row0 = aRow0 + aQ;
  const long col0 = bRow0 + bQ;
  #pragma unroll
  for (int i = 0; i < 4; ++i)
    #pragma unroll
    for (int j = 0; j < 4; ++j) {
      long rr = row0 + i * 16 + kq * 4;
      long cc = col0 + j * 16 + r15;
      #pragma unroll
      for (int g = 0; g < 4; ++g) {
        float v = acc[i][j][g];
        long idx = cOff + (rr + g) * ldc + cc;
        if (mode == 0) {
          Cf[idx] = v;
        } else {
          u16 h = f2bf(v);
          Chi[idx] = h;
          Clo[idx] = f2bf(v - bf2f(h));
        }
      }
    }
}

// Softmax over strictly-past scores -> Wx[t][b][t']; also zeroes grid barrier
__global__ __launch_bounds__(256) void k_softmax(const float* __restrict__ S,
    float* __restrict__ Wx, int* __restrict__ bar)
{
  if (blockIdx.x == 0 && threadIdx.x == 0) { bar[0] = 0; bar[1] = 0; }
  const int wv = threadIdx.x >> 6, lane = threadIdx.x & 63;
  const int idx = blockIdx.x * 4 + wv;        // = b*128 + t
  const int b = idx >> 7, t = idx & 127;
  const float* row = &S[(long)idx * 128];
  float v0 = (lane < t) ? row[lane] * 0.015625f : -1e30f;
  float v1 = (lane + 64 < t) ? row[lane + 64] * 0.015625f : -1e30f;
  float m = fmaxf(v0, v1);
  #pragma unroll
  for (int off = 32; off; off >>= 1) m = fmaxf(m, __shfl_xor(m, off));
  float e0 = (lane < t) ? expf(v0 - m) : 0.f;
  float e1 = (lane + 64 < t) ? expf(v1 - m) : 0.f;
  float s = e0 + e1;
  #pragma unroll
  for (int off = 32; off; off >>= 1) s += __shfl_xor(s, off);
  float inv = 1.f / fmaxf(s, 1e-9f);
  float* wr = &Wx[((long)t * 16 + b) * 128];
  wr[lane] = e0 * inv;
  wr[lane + 64] = e1 * inv;
}

// ---------------------------------------------------------------------------
// Persistent phase C: one block per 16 output cols (grid 256 = 1/CU).
// Wvo slice in REGISTERS (32 short8v/lane); VO history in LDS; one grid
// barrier per step. 512 thr = 8 waves, K split 8-way, 48 MFMA/wave/step.
// ---------------------------------------------------------------------------
__global__ __launch_bounds__(512, 2) void k_phaseC(
    const u16* __restrict__ Wvh, const u16* __restrict__ Wvl,
    const float* __restrict__ Wx,
    const u16* __restrict__ hoh, const u16* __restrict__ hol,
    u16* __restrict__ oh0, u16* __restrict__ ol0,
    u16* __restrict__ oh1, u16* __restrict__ ol1,
    float* __restrict__ fdest, int dmode, int* __restrict__ bar)
{
  __shared__ float VO_lds[128 * 256];        // [t][b*16+col]  128 KB
  __shared__ float vo_w[8][256];
  __shared__ float pctx[2][256];
  const int tid = threadIdx.x;
  const int lane = tid & 63, wv = tid >> 6;
  const int n0 = blockIdx.x * 16;
  const int r15 = lane & 15, kq = lane >> 4;
  const long kb = (long)wv * 512 + kq * 8;   // this lane's K base

  // Wvo slice -> registers (B-frag rows n0+r15; compile-time indices only)
  short8v Bh[16], Bl[16];
  {
    const u16* bh = Wvh + (long)(n0 + r15) * 4096 + kb;
    const u16* bl = Wvl + (long)(n0 + r15) * 4096 + kb;
    #pragma unroll
    for (int c = 0; c < 16; ++c) {
      Bh[c] = *(const short8v*)(bh + c * 32);
      Bl[c] = *(const short8v*)(bl + c * 32);
    }
  }
  const long abase = (long)r15 * 4096 + kb;  // A-frag base (row = batch r15)
  const int b8 = tid >> 4, col8 = tid & 15;  // (b, col) for tid<256

  // out_0 = tanh(ho_0) for my cols
  if (tid < 256) {
    float v = tanhf(bf2f(hoh[(long)b8 * 12288 + n0 + col8])
                  + bf2f(hol[(long)b8 * 12288 + n0 + col8]));
    u16 hh = f2bf(v);
    long oi = (long)b8 * 4096 + n0 + col8;
    oh0[oi] = hh; ol0[oi] = f2bf(v - bf2f(hh));
    if (dmode == 0) fdest[(long)b8 * 4096 + n0 + col8] = v;
    else            fdest[(long)b8 * 128 * 4096 + n0 + col8] = v;
  }
  gridbar(bar, 256);

  for (int t = 0; t < 127; ++t) {
    const u16* pah = ((t & 1) ? oh1 : oh0) + abase;
    const u16* pal = ((t & 1) ? ol1 : ol0) + abase;
    f32x4 acc = {0.f, 0.f, 0.f, 0.f};
    #pragma unroll
    for (int c = 0; c < 16; ++c) {
      short8v ah = *(const short8v*)(pah + c * 32);
      short8v al = *(const short8v*)(pal + c * 32);
      acc = __builtin_amdgcn_mfma_f32_16x16x32_bf16(ah, Bh[c], acc, 0, 0, 0);
      acc = __builtin_amdgcn_mfma_f32_16x16x32_bf16(ah, Bl[c], acc, 0, 0, 0);
      acc = __builtin_amdgcn_mfma_f32_16x16x32_bf16(al, Bh[c], acc, 0, 0, 0);
    }
    #pragma unroll
    for (int g = 0; g < 4; ++g)
      vo_w[wv][(kq * 4 + g) * 16 + r15] = acc[g];
    __syncthreads();
    float v = 0.f;
    if (tid < 256) {
      v = vo_w[0][tid] + vo_w[1][tid] + vo_w[2][tid] + vo_w[3][tid]
        + vo_w[4][tid] + vo_w[5][tid] + vo_w[6][tid] + vo_w[7][tid];
      VO_lds[t * 256 + tid] = v;
    }
    // partial mix over past vo (p=0: even t', p=1: odd t')
    {
      const int p = tid >> 8, id = tid & 255;
      const int b = id >> 4;
      const float* wrow = &Wx[((long)(t + 1) * 16 + b) * 128];
      float ctx = 0.f;
      for (int tp = p; tp < t; tp += 2)
        ctx += wrow[tp] * VO_lds[tp * 256 + id];
      pctx[p][id] = ctx;
    }
    __syncthreads();
    if (tid < 256) {
      const float* wrow = &Wx[((long)(t + 1) * 16 + b8) * 128];
      long hix = ((long)(t + 1) * 16 + b8) * 12288 + n0 + col8;
      float o = tanhf(bf2f(hoh[hix]) + bf2f(hol[hix])
                      + pctx[0][tid] + pctx[1][tid] + wrow[t] * v);
      u16 hh = f2bf(o);
      long oi = (long)b8 * 4096 + n0 + col8;
      if ((t + 1) & 1) { oh1[oi] = hh; ol1[oi] = f2bf(o - bf2f(hh)); }
      else             { oh0[oi] = hh; ol0[oi] = f2bf(o - bf2f(hh)); }
      if (dmode == 0) fdest[((long)(t + 1) * 16 + b8) * 4096 + n0 + col8] = o;
      else            fdest[((long)b8 * 128 + (t + 1)) * 4096 + n0 + col8] = o;
    }
    gridbar(bar, 256);
  }
}

// ---------------------------------------------------------------------------
extern "C" void kernel_launch(void* const* d_in, const int* in_sizes, int n_in,
                              void* d_out, int out_size, void* d_ws, size_t ws_size,
                              hipStream_t stream)
{
  (void)in_sizes; (void)n_in; (void)out_size;
  if (ws_size < 472383488UL) return;  // need ~451 MiB scratch
  char* ws = (char*)d_ws;
  // Stacked B^T for the fused Q|K|HO GEMM: [12288][4096] split bf16
  u16* WT_hi = (u16*)(ws + 0UL);               // 96 MB
  u16* WT_lo = (u16*)(ws + 100663296UL);       // 96 MB
  u16* WV_hi = (u16*)(ws + 33554432UL);        // reuses dead WT rows
  u16* WV_lo = (u16*)(ws + 134217728UL);
  u16* QKOh  = (u16*)(ws + 201326592UL);       // [2048][12288] hi (48 MB)
  u16* QKOl  = (u16*)(ws + 251658240UL);       // lo (48 MB)
  u16* Wvo_hi = (u16*)(ws + 301989888UL);      // 32 MB (reused per layer)
  u16* Wvo_lo = (u16*)(ws + 335544320UL);      // 32 MB
  u16* Hs_hi = (u16*)(ws + 369098752UL);       // 16 MB
  u16* Hs_lo = (u16*)(ws + 385875968UL);
  float* Sb   = (float*)(ws + 402653184UL);
  float* Wmx  = (float*)(ws + 403701760UL);
  int*   bar  = (int*)(ws + 404750336UL);
  float* OUT0 = (float*)(ws + 438304768UL);
  u16* obh[2] = {(u16*)(ws + 471859200UL), (u16*)(ws + 472121344UL)};
  u16* obl[2] = {(u16*)(ws + 471990272UL), (u16*)(ws + 472252416UL)};
  float* dout = (float*)d_out;
  const float* x_flat = (const float*)d_in[0];

  for (int l = 0; l < 2; ++l) {
    const float* cw = (const float*)d_in[1 + l * 6];
    const float* cb = (const float*)d_in[2 + l * 6];
    const float* wq = (const float*)d_in[3 + l * 6];
    const float* wk = (const float*)d_in[4 + l * 6];
    const float* wv = (const float*)d_in[5 + l * 6];
    const float* wo = (const float*)d_in[6 + l * 6];
    const int cin = (l == 0) ? 17 : 32;

    // Phase A: ConvLSTM recurrence -> split h_vec rows
    hipLaunchKernelGGL(k_conv, dim3(256), dim3(256), 0, stream,
        cin, l, (l == 0) ? x_flat : OUT0, cw, cb, Hs_hi, Hs_lo);

    // Phase B1: stack wq^T | wk^T | wo_h^T into WT, then ONE fused GEMM
    hipLaunchKernelGGL(k_tsplit, dim3(16384), dim3(256), 0, stream,
        wq, WT_hi, WT_lo);
    hipLaunchKernelGGL(k_tsplit, dim3(16384), dim3(256), 0, stream,
        wk, WT_hi + 16777216UL, WT_lo + 16777216UL);
    hipLaunchKernelGGL(k_tsplit, dim3(16384), dim3(256), 0, stream,
        wo, WT_hi + 33554432UL, WT_lo + 33554432UL);
    hipLaunchKernelGGL(k_gemm, dim3(16 * 96, 1), dim3(256), 0, stream,
        Hs_hi, Hs_lo, 4096L, 0L, WT_hi, WT_lo, 4096L, 0L,
        (float*)nullptr, QKOh, QKOl, 12288L, 0L, 96, 1);

    // Phase B2: composite Wvo^T = (wv @ wo_c)^T
    hipLaunchKernelGGL(k_tsplit, dim3(16384), dim3(256), 0, stream,
        wo + 16777216UL, WT_hi, WT_lo);                       // wo_c^T
    hipLaunchKernelGGL(k_split, dim3(16384), dim3(256), 0, stream, wv, WV_hi, WV_lo);
    hipLaunchKernelGGL(k_gemm, dim3(32 * 32, 1), dim3(256), 0, stream,
        WT_hi, WT_lo, 4096L, 0L, WV_hi, WV_lo, 4096L, 0L,
        (float*)nullptr, Wvo_hi, Wvo_lo, 4096L, 0L, 32, 1);

    // Scores via batched MFMA GEMM: S[b][t][t'] = Q[t,b,:]·K[t',b,:]
    hipLaunchKernelGGL(k_gemm, dim3(1, 16), dim3(256), 0, stream,
        QKOh, QKOl, 196608L, 12288L, QKOh + 4096, QKOl + 4096, 196608L, 12288L,
        Sb, (u16*)nullptr, (u16*)nullptr, 128L, 16384L, 1, 0);
    hipLaunchKernelGGL(k_softmax, dim3(512), dim3(256), 0, stream, Sb, Wmx, bar);

    // Phase C: ONE persistent kernel (grid barrier per step)
    hipLaunchKernelGGL(k_phaseC, dim3(256), dim3(512), 0, stream,
        Wvo_hi, Wvo_lo, Wmx, QKOh + 8192, QKOl + 8192,
        obh[0], obl[0], obh[1], obl[1],
        (l == 0) ? OUT0 : dout, l, bar);
  }
}

// Round 5
// 6725.581 us; speedup vs baseline: 1.9771x; 1.9771x over previous
//
#include <hip/hip_runtime.h>

typedef unsigned short u16;
typedef unsigned int u32;
typedef __attribute__((ext_vector_type(8))) short short8v;   // 8 bf16 (4 VGPR) MFMA frag
typedef __attribute__((ext_vector_type(4))) float f32x4;     // MFMA acc
typedef __attribute__((ext_vector_type(8))) u16 ush8;
typedef __attribute__((ext_vector_type(4))) u16 ush4;

__device__ __forceinline__ u16 f2bf(float x) {               // RNE f32->bf16
  u32 u = __builtin_bit_cast(u32, x);
  return (u16)((u + 0x7FFFu + ((u >> 16) & 1u)) >> 16);
}
__device__ __forceinline__ float bf2f(u16 h) {
  u32 u = ((u32)h) << 16;
  return __builtin_bit_cast(float, u);
}
__device__ __forceinline__ float sigm(float x) { return 1.f / (1.f + expf(-x)); }

typedef const __attribute__((address_space(1))) void gv_t;
typedef __attribute__((address_space(3))) void lv_t;
__device__ __forceinline__ void gload16(const void* g, void* l) {
  __builtin_amdgcn_global_load_lds((gv_t*)g, (lv_t*)l, 16, 0, 0);
}

// --- device-coherent (L2-bypass / write-through) access helpers -------------
__device__ __forceinline__ u32 ldsc32(const u32* p) {
  u32 v;
  asm volatile("global_load_dword %0, %1, off sc0 sc1\n\ts_waitcnt vmcnt(0)"
               : "=v"(v) : "v"(p) : "memory");
  return v;
}
__device__ __forceinline__ void stsc32(u32* p, u32 v) {
  asm volatile("global_store_dword %0, %1, off sc0 sc1" :: "v"(p), "v"(v) : "memory");
}
__device__ __forceinline__ void stsc16(u16* p, u16 v) {
  asm volatile("global_store_short %0, %1, off sc0 sc1" :: "v"(p), "v"(v) : "memory");
}

// ---------------------------------------------------------------------------
// ConvLSTM recurrence: one WG per (b, row). Computes h for all t, stores
// split-bf16 h_vec rows [t*16+b][4096].  d = r*256 + ch*16 + col.
// ---------------------------------------------------------------------------
__global__ __launch_bounds__(256) void k_conv(int cin, int xmode,
    const float* __restrict__ xin, const float* __restrict__ cw,
    const float* __restrict__ cb, u16* __restrict__ hhi, u16* __restrict__ hlo)
{
  __shared__ float zb[32 * 18];        // cin x (16+2 pad)
  __shared__ float wb[64 * 32 * 3];
  __shared__ float bb[64];
  const int tid = threadIdx.x;
  const int b = blockIdx.x >> 4, r = blockIdx.x & 15;
  const int ch = tid >> 4, col = tid & 15;
  const int cx = cin - 16;
  for (int i = tid; i < 64 * cin * 3; i += 256) wb[i] = cw[i];
  if (tid < 64) bb[tid] = cb[tid];
  for (int i = tid; i < cin * 18; i += 256) zb[i] = 0.f;  // includes pad cols
  __syncthreads();
  float h = 0.f, c = 0.f;
  for (int t = 0; t < 128; ++t) {
    if (xmode == 0) {
      if (ch == 0) zb[col + 1] = xin[((long)b * 128 + t) * 256 + r * 16 + col];
    } else {
      zb[ch * 18 + col + 1] = xin[((long)t * 16 + b) * 4096 + r * 256 + ch * 16 + col];
    }
    zb[(cx + ch) * 18 + col + 1] = h;
    __syncthreads();
    float a0 = bb[ch], a1 = bb[16 + ch], a2 = bb[32 + ch], a3 = bb[48 + ch];
    for (int ic = 0; ic < cin; ++ic) {
      float z0 = zb[ic * 18 + col], z1 = zb[ic * 18 + col + 1], z2 = zb[ic * 18 + col + 2];
      const float* w0 = &wb[((0 * 16 + ch) * cin + ic) * 3];
      const float* w1 = &wb[((1 * 16 + ch) * cin + ic) * 3];
      const float* w2 = &wb[((2 * 16 + ch) * cin + ic) * 3];
      const float* w3 = &wb[((3 * 16 + ch) * cin + ic) * 3];
      a0 += z0 * w0[0] + z1 * w0[1] + z2 * w0[2];
      a1 += z0 * w1[0] + z1 * w1[1] + z2 * w1[2];
      a2 += z0 * w2[0] + z1 * w2[1] + z2 * w2[2];
      a3 += z0 * w3[0] + z1 * w3[1] + z2 * w3[2];
    }
    __syncthreads();
    c = sigm(a1) * c + sigm(a0) * tanhf(a2);   // i,f,g,o gate order
    h = sigm(a3) * tanhf(c);
    long idx = ((long)t * 16 + b) * 4096 + (long)r * 256 + ch * 16 + col;
    u16 hh = f2bf(h);
    hhi[idx] = hh;
    hlo[idx] = f2bf(h - bf2f(hh));
  }
}

// ---------------------------------------------------------------------------
// Transpose + split: W[4096][4096] fp32 (row k, col n) -> WT_hi/lo[n][k] bf16
// ---------------------------------------------------------------------------
__global__ __launch_bounds__(256) void k_tsplit(const float* __restrict__ W,
    u16* __restrict__ hi, u16* __restrict__ lo)
{
  __shared__ float tb[32][33];
  const int tn = blockIdx.x & 127, tk = blockIdx.x >> 7;
  const int n0 = tn * 32, k0 = tk * 32;
  const int lr = threadIdx.x >> 5, lc = threadIdx.x & 31;
  #pragma unroll
  for (int i = 0; i < 4; ++i)
    tb[lr + i * 8][lc] = W[(long)(k0 + lr + i * 8) * 4096 + n0 + lc];
  __syncthreads();
  #pragma unroll
  for (int i = 0; i < 4; ++i) {
    int n = lr + i * 8;
    float v = tb[lc][n];
    long idx = (long)(n0 + n) * 4096 + k0 + lc;
    u16 h = f2bf(v);
    hi[idx] = h;
    lo[idx] = f2bf(v - bf2f(h));
  }
}

// Elementwise split (no transpose) for wv
__global__ __launch_bounds__(256) void k_split(const float* __restrict__ W,
    u16* __restrict__ hi, u16* __restrict__ lo)
{
  long i = ((long)blockIdx.x * 256 + threadIdx.x) * 4;
  const float4 v = *(const float4*)&W[i];
  u16 h0 = f2bf(v.x), h1 = f2bf(v.y), h2 = f2bf(v.z), h3 = f2bf(v.w);
  ush4 hv = {h0, h1, h2, h3};
  ush4 lv = {f2bf(v.x - bf2f(h0)), f2bf(v.y - bf2f(h1)),
             f2bf(v.z - bf2f(h2)), f2bf(v.w - bf2f(h3))};
  *(ush4*)&hi[i] = hv;
  *(ush4*)&lo[i] = lv;
}

// ---------------------------------------------------------------------------
// Split-bf16 GEMM via global_load_lds + XOR-swizzled, DOUBLE-BUFFERED LDS.
// C[M][N] = A[M][4096] * B[N][4096]^T, A/B split hi/lo bf16. K = 4096.
// grid.x = mT * nTc + nT;  grid.y = batch (strided A/B/C).
// mode 0: fp32 C.  mode 1: split hi/lo bf16 C.
// ---------------------------------------------------------------------------
__global__ __launch_bounds__(256) void k_gemm(
    const u16* __restrict__ Ahi, const u16* __restrict__ Alo, long lda, long aBS,
    const u16* __restrict__ Bhi, const u16* __restrict__ Blo, long ldb, long bBS,
    float* __restrict__ Cf, u16* __restrict__ Chi, u16* __restrict__ Clo,
    long ldc, long cBS, int nTc, int mode)
{
  __shared__ __align__(16) u16 lds[2][16384];   // per buf: PA @0, PB @8192
  const int tid = threadIdx.x;
  const int lane = tid & 63;
  const int wv = tid >> 6;
  const int bx = blockIdx.x;
  const int nT = bx % nTc;
  const int mT = bx / nTc;
  const long aOff = (long)blockIdx.y * aBS;
  const long bOff = (long)blockIdx.y * bBS;
  const long cOff = (long)blockIdx.y * cBS;
  const long aRow0 = (long)mT * 128;
  const long bRow0 = (long)nT * 128;

  // per-lane pre-swizzled global staging source (rule #21: swz both sides)
  const int l8 = lane >> 3;             // row-within-8 AND swizzle key
  const int cslot = (lane & 7) ^ l8;    // logical chunk this lane fetches
  const int ck = (cslot & 3) * 8;
  const u16* aSrc = ((cslot < 4) ? Ahi : Alo) + aOff + (aRow0 + wv * 32 + l8) * lda + ck;
  const u16* bSrc = ((cslot < 4) ? Bhi : Blo) + bOff + (bRow0 + wv * 32 + l8) * ldb + ck;
  const int ldsAo = wv * 2048;          // wave wv stages rows wv*32..+31
  const int ldsBo = 8192 + wv * 2048;

  const int r15 = lane & 15, kq = lane >> 4;
  const int s7 = r15 & 7;
  const int oHi = (kq ^ s7) * 8;        // swizzled u16 offset of hi chunk
  const int oLo = ((4 + kq) ^ s7) * 8;  // swizzled u16 offset of lo chunk
  const int aQ = (wv >> 1) * 64;        // waveM*64
  const int bQ = (wv & 1) * 64;         // waveN*64

  f32x4 acc[4][4] = {};

#define STAGE(buf, kofs)                                                     \
  {                                                                          \
    const u16* sa = aSrc + (kofs);                                           \
    const u16* sb = bSrc + (kofs);                                           \
    u16* la = &lds[buf][ldsAo];                                              \
    u16* lb = &lds[buf][ldsBo];                                              \
    gload16(sa,            la);        gload16(sa +  8 * lda, la + 512);     \
    gload16(sa + 16 * lda, la + 1024); gload16(sa + 24 * lda, la + 1536);    \
    gload16(sb,            lb);        gload16(sb +  8 * ldb, lb + 512);     \
    gload16(sb + 16 * ldb, lb + 1024); gload16(sb + 24 * ldb, lb + 1536);    \
  }

  STAGE(0, 0)
  __syncthreads();                      // vmcnt(0) drained: buf0 ready
  int cur = 0;
  for (int k0 = 0; k0 < 4096; k0 += 32) {
    if (k0 + 32 < 4096) STAGE(cur ^ 1, k0 + 32)   // flies during MFMA phase
    const u16* L = &lds[cur][0];
    short8v bh[4], bl[4];
    #pragma unroll
    for (int j = 0; j < 4; ++j) {
      int rb = 8192 + (bQ + j * 16 + r15) * 64;
      bh[j] = *(const short8v*)&L[rb + oHi];
      bl[j] = *(const short8v*)&L[rb + oLo];
    }
    #pragma unroll
    for (int i = 0; i < 4; ++i) {
      int ra = (aQ + i * 16 + r15) * 64;
      short8v ah = *(const short8v*)&L[ra + oHi];
      short8v al = *(const short8v*)&L[ra + oLo];
      #pragma unroll
      for (int j = 0; j < 4; ++j) {
        acc[i][j] = __builtin_amdgcn_mfma_f32_16x16x32_bf16(ah, bh[j], acc[i][j], 0, 0, 0);
        acc[i][j] = __builtin_amdgcn_mfma_f32_16x16x32_bf16(ah, bl[j], acc[i][j], 0, 0, 0);
        acc[i][j] = __builtin_amdgcn_mfma_f32_16x16x32_bf16(al, bh[j], acc[i][j], 0, 0, 0);
      }
    }
    __syncthreads();   // next buf staged + all reads of cur done
    cur ^= 1;
  }
#undef STAGE
  // epilogue: D row=(lane>>4)*4+reg, col=lane&15 (measured m89 layout)
  const long row0 = aRow0 + aQ;
  const long col0 = bRow0 + bQ;
  #pragma unroll
  for (int i = 0; i < 4; ++i)
    #pragma unroll
    for (int j = 0; j < 4; ++j) {
      long rr = row0 + i * 16 + kq * 4;
      long cc = col0 + j * 16 + r15;
      #pragma unroll
      for (int g = 0; g < 4; ++g) {
        float v = acc[i][j][g];
        long idx = cOff + (rr + g) * ldc + cc;
        if (mode == 0) {
          Cf[idx] = v;
        } else {
          u16 h = f2bf(v);
          Chi[idx] = h;
          Clo[idx] = f2bf(v - bf2f(h));
        }
      }
    }
}

// Softmax over strictly-past scores -> Wx[t][b][t']; also zeroes barrier flags
__global__ __launch_bounds__(256) void k_softmax(const float* __restrict__ S,
    float* __restrict__ Wx, u32* __restrict__ flags)
{
  if (blockIdx.x == 0) {
    flags[threadIdx.x] = 0;
    if (threadIdx.x == 0) flags[256] = 0;
  }
  const int wv = threadIdx.x >> 6, lane = threadIdx.x & 63;
  const int idx = blockIdx.x * 4 + wv;        // = b*128 + t
  const int b = idx >> 7, t = idx & 127;
  const float* row = &S[(long)idx * 128];
  float v0 = (lane < t) ? row[lane] * 0.015625f : -1e30f;
  float v1 = (lane + 64 < t) ? row[lane + 64] * 0.015625f : -1e30f;
  float m = fmaxf(v0, v1);
  #pragma unroll
  for (int off = 32; off; off >>= 1) m = fmaxf(m, __shfl_xor(m, off));
  float e0 = (lane < t) ? expf(v0 - m) : 0.f;
  float e1 = (lane + 64 < t) ? expf(v1 - m) : 0.f;
  float s = e0 + e1;
  #pragma unroll
  for (int off = 32; off; off >>= 1) s += __shfl_xor(s, off);
  float inv = 1.f / fmaxf(s, 1e-9f);
  float* wr = &Wx[((long)t * 16 + b) * 128];
  wr[lane] = e0 * inv;
  wr[lane + 64] = e1 * inv;
}

// ---------------------------------------------------------------------------
// Persistent phase C. grid 256 (1 block/CU by LDS), 512 thr = 8 waves.
// Wvo slice PINNED in registers (asm); out exchange via sc0sc1 (IF$-coherent)
// stores/loads; flag-tree grid barrier (no atomics, no threadfence).
// ---------------------------------------------------------------------------
__global__ __launch_bounds__(512, 2) void k_phaseC(
    const u16* __restrict__ Wvh, const u16* __restrict__ Wvl,
    const float* __restrict__ Wx,
    const u16* __restrict__ hoh, const u16* __restrict__ hol,
    u16* __restrict__ oh0, u16* __restrict__ ol0,
    u16* __restrict__ oh1, u16* __restrict__ ol1,
    float* __restrict__ fdest, int dmode, u32* __restrict__ flags)
{
  __shared__ float VO_lds[128 * 256];        // [t][b*16+col]  128 KB
  __shared__ float vo_w[8][256];
  __shared__ float pctx[2][256];
  const int tid = threadIdx.x;
  const int lane = tid & 63, wv = tid >> 6;
  const int n0 = blockIdx.x * 16;
  const int r15 = lane & 15, kq = lane >> 4;
  const long kb = (long)wv * 512 + kq * 8;   // this lane's K base

  // Wvo slice -> registers, PINNED via asm (cannot be rematerialized)
  short8v Bh[16], Bl[16];
  {
    const u16* bh = Wvh + (long)(n0 + r15) * 4096 + kb;
    const u16* bl = Wvl + (long)(n0 + r15) * 4096 + kb;
    #pragma unroll
    for (int c = 0; c < 16; ++c) {
      Bh[c] = *(const short8v*)(bh + c * 32);
      Bl[c] = *(const short8v*)(bl + c * 32);
    }
    #pragma unroll
    for (int c = 0; c < 16; ++c) {
      asm volatile("" : "+v"(Bh[c]));
      asm volatile("" : "+v"(Bl[c]));
    }
  }
  const long abase = (long)r15 * 4096 + kb;  // A-frag base (row = batch r15)
  const int b8 = tid >> 4, col8 = tid & 15;  // (b, col) for tid<256

#define GBAR(n)                                                              \
  {                                                                          \
    asm volatile("s_waitcnt vmcnt(0)" ::: "memory");                         \
    __syncthreads();                                                         \
    if (blockIdx.x == 0) {                                                   \
      if (tid == 0) stsc32(&flags[0], (n));                                  \
      if (tid < 256) {                                                       \
        while (ldsc32(&flags[tid]) < (n)) __builtin_amdgcn_s_sleep(4);       \
      }                                                                      \
      __syncthreads();                                                       \
      if (tid == 0) {                                                        \
        asm volatile("s_waitcnt vmcnt(0)" ::: "memory");                     \
        stsc32(&flags[256], (n));                                            \
      }                                                                      \
    } else if (tid == 0) {                                                   \
      stsc32(&flags[blockIdx.x], (n));                                       \
      while (ldsc32(&flags[256]) < (n)) __builtin_amdgcn_s_sleep(4);         \
    }                                                                        \
    __syncthreads();                                                         \
  }

  // out_0 = tanh(ho_0) for my cols (sc stores -> IF$)
  if (tid < 256) {
    float v = tanhf(bf2f(hoh[(long)b8 * 12288 + n0 + col8])
                  + bf2f(hol[(long)b8 * 12288 + n0 + col8]));
    u16 hh = f2bf(v);
    long oi = (long)b8 * 4096 + n0 + col8;
    stsc16(&oh0[oi], hh);
    stsc16(&ol0[oi], f2bf(v - bf2f(hh)));
    if (dmode == 0) fdest[(long)b8 * 4096 + n0 + col8] = v;
    else            fdest[(long)b8 * 128 * 4096 + n0 + col8] = v;
  }
  u32 bn = 1;
  GBAR(bn) ++bn;

#define LD2(dh, dl, OFS)                                                     \
  asm volatile("global_load_dwordx4 %0, %2, off offset:" OFS " sc0 sc1\n\t"  \
               "global_load_dwordx4 %1, %3, off offset:" OFS " sc0 sc1"      \
               : "=v"(dh), "=v"(dl) : "v"(pah), "v"(pal));
#define WAITSB(N)                                                            \
  asm volatile("s_waitcnt vmcnt(" #N ")" ::: "memory");                      \
  __builtin_amdgcn_sched_barrier(0);
#define MG(S, B0)                                                            \
  _Pragma("unroll")                                                          \
  for (int c = 0; c < 4; ++c) {                                              \
    acc = __builtin_amdgcn_mfma_f32_16x16x32_bf16(S##h[c], Bh[(B0) + c], acc, 0, 0, 0); \
    acc = __builtin_amdgcn_mfma_f32_16x16x32_bf16(S##h[c], Bl[(B0) + c], acc, 0, 0, 0); \
    acc = __builtin_amdgcn_mfma_f32_16x16x32_bf16(S##l[c], Bh[(B0) + c], acc, 0, 0, 0); \
  }

  for (int t = 0; t < 127; ++t) {
    const u16* pah = ((t & 1) ? oh1 : oh0) + abase;
    const u16* pal = ((t & 1) ? ol1 : ol0) + abase;
    f32x4 acc = {0.f, 0.f, 0.f, 0.f};
    short8v x0h[4], x0l[4], x1h[4], x1l[4];
    LD2(x0h[0], x0l[0], "0")   LD2(x0h[1], x0l[1], "64")
    LD2(x0h[2], x0l[2], "128") LD2(x0h[3], x0l[3], "192")
    LD2(x1h[0], x1l[0], "256") LD2(x1h[1], x1l[1], "320")
    LD2(x1h[2], x1l[2], "384") LD2(x1h[3], x1l[3], "448")
    WAITSB(8)
    MG(x0, 0)
    LD2(x0h[0], x0l[0], "512") LD2(x0h[1], x0l[1], "576")
    LD2(x0h[2], x0l[2], "640") LD2(x0h[3], x0l[3], "704")
    WAITSB(8)
    MG(x1, 4)
    LD2(x1h[0], x1l[0], "768") LD2(x1h[1], x1l[1], "832")
    LD2(x1h[2], x1l[2], "896") LD2(x1h[3], x1l[3], "960")
    WAITSB(8)
    MG(x0, 8)
    WAITSB(0)
    MG(x1, 12)

    #pragma unroll
    for (int g = 0; g < 4; ++g)
      vo_w[wv][(kq * 4 + g) * 16 + r15] = acc[g];
    __syncthreads();
    float v = 0.f;
    if (tid < 256) {
      v = vo_w[0][tid] + vo_w[1][tid] + vo_w[2][tid] + vo_w[3][tid]
        + vo_w[4][tid] + vo_w[5][tid] + vo_w[6][tid] + vo_w[7][tid];
      VO_lds[t * 256 + tid] = v;
    }
    // partial mix over past vo (p=0: even t', p=1: odd t')
    {
      const int p = tid >> 8, id = tid & 255;
      const int b = id >> 4;
      const float* wrow = &Wx[((long)(t + 1) * 16 + b) * 128];
      float ctx = 0.f;
      for (int tp = p; tp < t; tp += 2)
        ctx += wrow[tp] * VO_lds[tp * 256 + id];
      pctx[p][id] = ctx;
    }
    __syncthreads();
    if (tid < 256) {
      const float* wrow = &Wx[((long)(t + 1) * 16 + b8) * 128];
      long hix = ((long)(t + 1) * 16 + b8) * 12288 + n0 + col8;
      float o = tanhf(bf2f(hoh[hix]) + bf2f(hol[hix])
                      + pctx[0][tid] + pctx[1][tid] + wrow[t] * v);
      u16 hh = f2bf(o);
      long oi = (long)b8 * 4096 + n0 + col8;
      if ((t + 1) & 1) { stsc16(&oh1[oi], hh); stsc16(&ol1[oi], f2bf(o - bf2f(hh))); }
      else             { stsc16(&oh0[oi], hh); stsc16(&ol0[oi], f2bf(o - bf2f(hh))); }
      if (dmode == 0) fdest[((long)(t + 1) * 16 + b8) * 4096 + n0 + col8] = o;
      else            fdest[((long)b8 * 128 + (t + 1)) * 4096 + n0 + col8] = o;
    }
    if (t < 126) { GBAR(bn) ++bn; }
  }
#undef GBAR
#undef LD2
#undef WAITSB
#undef MG
}

// ---------------------------------------------------------------------------
extern "C" void kernel_launch(void* const* d_in, const int* in_sizes, int n_in,
                              void* d_out, int out_size, void* d_ws, size_t ws_size,
                              hipStream_t stream)
{
  (void)in_sizes; (void)n_in; (void)out_size;
  if (ws_size < 472383488UL) return;  // need ~451 MiB scratch
  char* ws = (char*)d_ws;
  // Stacked B^T for the fused Q|K|HO GEMM: [12288][4096] split bf16
  u16* WT_hi = (u16*)(ws + 0UL);               // 96 MB
  u16* WT_lo = (u16*)(ws + 100663296UL);       // 96 MB
  u16* WV_hi = (u16*)(ws + 33554432UL);        // reuses dead WT rows
  u16* WV_lo = (u16*)(ws + 134217728UL);
  u16* QKOh  = (u16*)(ws + 201326592UL);       // [2048][12288] hi (48 MB)
  u16* QKOl  = (u16*)(ws + 251658240UL);       // lo (48 MB)
  u16* Wvo_hi = (u16*)(ws + 301989888UL);      // 32 MB (reused per layer)
  u16* Wvo_lo = (u16*)(ws + 335544320UL);      // 32 MB
  u16* Hs_hi = (u16*)(ws + 369098752UL);       // 16 MB
  u16* Hs_lo = (u16*)(ws + 385875968UL);
  float* Sb   = (float*)(ws + 402653184UL);
  float* Wmx  = (float*)(ws + 403701760UL);
  u32*   flg  = (u32*)(ws + 404750336UL);
  float* OUT0 = (float*)(ws + 438304768UL);
  u16* obh[2] = {(u16*)(ws + 471859200UL), (u16*)(ws + 472121344UL)};
  u16* obl[2] = {(u16*)(ws + 471990272UL), (u16*)(ws + 472252416UL)};
  float* dout = (float*)d_out;
  const float* x_flat = (const float*)d_in[0];

  for (int l = 0; l < 2; ++l) {
    const float* cw = (const float*)d_in[1 + l * 6];
    const float* cb = (const float*)d_in[2 + l * 6];
    const float* wq = (const float*)d_in[3 + l * 6];
    const float* wk = (const float*)d_in[4 + l * 6];
    const float* wv = (const float*)d_in[5 + l * 6];
    const float* wo = (const float*)d_in[6 + l * 6];
    const int cin = (l == 0) ? 17 : 32;

    // Phase A: ConvLSTM recurrence -> split h_vec rows
    hipLaunchKernelGGL(k_conv, dim3(256), dim3(256), 0, stream,
        cin, l, (l == 0) ? x_flat : OUT0, cw, cb, Hs_hi, Hs_lo);

    // Phase B1: stack wq^T | wk^T | wo_h^T into WT, then ONE fused GEMM
    hipLaunchKernelGGL(k_tsplit, dim3(16384), dim3(256), 0, stream,
        wq, WT_hi, WT_lo);
    hipLaunchKernelGGL(k_tsplit, dim3(16384), dim3(256), 0, stream,
        wk, WT_hi + 16777216UL, WT_lo + 16777216UL);
    hipLaunchKernelGGL(k_tsplit, dim3(16384), dim3(256), 0, stream,
        wo, WT_hi + 33554432UL, WT_lo + 33554432UL);
    hipLaunchKernelGGL(k_gemm, dim3(16 * 96, 1), dim3(256), 0, stream,
        Hs_hi, Hs_lo, 4096L, 0L, WT_hi, WT_lo, 4096L, 0L,
        (float*)nullptr, QKOh, QKOl, 12288L, 0L, 96, 1);

    // Phase B2: composite Wvo^T = (wv @ wo_c)^T
    hipLaunchKernelGGL(k_tsplit, dim3(16384), dim3(256), 0, stream,
        wo + 16777216UL, WT_hi, WT_lo);                       // wo_c^T
    hipLaunchKernelGGL(k_split, dim3(16384), dim3(256), 0, stream, wv, WV_hi, WV_lo);
    hipLaunchKernelGGL(k_gemm, dim3(32 * 32, 1), dim3(256), 0, stream,
        WT_hi, WT_lo, 4096L, 0L, WV_hi, WV_lo, 4096L, 0L,
        (float*)nullptr, Wvo_hi, Wvo_lo, 4096L, 0L, 32, 1);

    // Scores via batched MFMA GEMM: S[b][t][t'] = Q[t,b,:]·K[t',b,:]
    hipLaunchKernelGGL(k_gemm, dim3(1, 16), dim3(256), 0, stream,
        QKOh, QKOl, 196608L, 12288L, QKOh + 4096, QKOl + 4096, 196608L, 12288L,
        Sb, (u16*)nullptr, (u16*)nullptr, 128L, 16384L, 1, 0);
    hipLaunchKernelGGL(k_softmax, dim3(512), dim3(256), 0, stream, Sb, Wmx, flg);

    // Phase C: ONE persistent kernel (flag-tree grid barrier per step)
    hipLaunchKernelGGL(k_phaseC, dim3(256), dim3(512), 0, stream,
        Wvo_hi, Wvo_lo, Wmx, QKOh + 8192, QKOl + 8192,
        obh[0], obl[0], obh[1], obl[1],
        (l == 0) ? OUT0 : dout, l, flg);
  }
}